// Round 2
// baseline (547.841 us; speedup 1.0000x reference)
//
#include <hip/hip_runtime.h>
#include <math.h>

// Problem shape (from reference setup_inputs): B=65536 rows, C=1000 cols, fp32.
#define C_DIM 1000
#define NV4   (C_DIM / 4)      // 250 float4 per row
#define WPB   4                // waves per block
#define RPW   8                // rows per wave, software-pipelined
#define PAD_O (-100.0f)        // exp(PAD_O) flushes to 0; with t=0 contributes nothing
#define LOG2E 1.44269504088896340736f
#define LN2   0.69314718055994530942f

__device__ __forceinline__ float wave_sum(float v) {
#pragma unroll
    for (int off = 32; off > 0; off >>= 1)
        v += __shfl_xor(v, off, 64);
    return v;
}

// Five interleaved butterfly chains — DS latency overlapped 5-wide.
__device__ __forceinline__ void wave_sum5(float v[5]) {
#pragma unroll
    for (int off = 32; off > 0; off >>= 1) {
        float x[5];
#pragma unroll
        for (int i = 0; i < 5; ++i) x[i] = __shfl_xor(v[i], off, 64);
#pragma unroll
        for (int i = 0; i < 5; ++i) v[i] += x[i];
    }
}

// One wave = one row at a time, RPW rows sequentially, with row i+1's global
// loads issued BEFORE row i's compute (register double-buffer). This keeps
// memory requests in flight during the exp/log phases and breaks the
// load-phase/compute-phase convoy that capped both pipes at ~40%/21%.
//
// Math (base-2 domain, u = o*log2e so exp->v_exp_f32, log->v_log_f32 raw):
//   S    = sum_neg 2^u            (only wave-reduced value needed mid-row)
//   pass2 over ALL 1024 slots: lsum = sum_k log2(S+ep_k), ltw = sum_k tp_k*log2(S+ep_k)
//   sum_p lse2_p = lsum - (1024-P)*log2(S)    (negatives+pads contribute log2(S))
//   sum_p loss_p = ln2*[ Tneg*sum_p lse2_p + ltw - P*aneg_u - apos_u ]
__global__ __launch_bounds__(256, 5) void mvce_rows(
    const float* __restrict__ outp, const float* __restrict__ tgtp,
    float* __restrict__ partial)
{
    const int lane = threadIdx.x & 63;
    const int wave = threadIdx.x >> 6;
    const size_t row0 = (size_t)(blockIdx.x * WPB + wave) * RPW;

    const float4* __restrict__ o4 = reinterpret_cast<const float4*>(outp) + row0 * NV4;
    const float4* __restrict__ t4 = reinterpret_cast<const float4*>(tgtp) + row0 * NV4;

    float4 ov[2][4], tv[2][4];

    // Prologue: load row 0 into buffer 0.
#pragma unroll
    for (int it = 0; it < 4; ++it) {
        const int j = lane + 64 * it;
        if (j < NV4) { ov[0][it] = o4[j]; tv[0][it] = t4[j]; }
        else {
            ov[0][it] = make_float4(PAD_O, PAD_O, PAD_O, PAD_O);
            tv[0][it] = make_float4(0.f, 0.f, 0.f, 0.f);
        }
    }

    float wacc = 0.0f;

#pragma unroll
    for (int i = 0; i < RPW; ++i) {
        const int cur = i & 1, nxt = cur ^ 1;

        // ---- Prefetch row i+1 (issued before any of row i's compute) ----
        if (i + 1 < RPW) {
            const float4* __restrict__ on = o4 + (size_t)(i + 1) * NV4;
            const float4* __restrict__ tn = t4 + (size_t)(i + 1) * NV4;
#pragma unroll
            for (int it = 0; it < 4; ++it) {
                const int j = lane + 64 * it;
                if (j < NV4) { ov[nxt][it] = on[j]; tv[nxt][it] = tn[j]; }
                else {
                    ov[nxt][it] = make_float4(PAD_O, PAD_O, PAD_O, PAD_O);
                    tv[nxt][it] = make_float4(0.f, 0.f, 0.f, 0.f);
                }
            }
        }
        __builtin_amdgcn_sched_barrier(0);   // prefetch stays above compute

        // ---- Pass 1 on row i (registers) ----
        float ep[16], tp[16];
        float sneg = 0.f, ta = 0.f, tpos = 0.f, aa = 0.f, ap = 0.f;
        int pcnt = 0;
#pragma unroll
        for (int it = 0; it < 4; ++it) {
            const float oq[4] = {ov[cur][it].x, ov[cur][it].y, ov[cur][it].z, ov[cur][it].w};
            const float tq[4] = {tv[cur][it].x, tv[cur][it].y, tv[cur][it].z, tv[cur][it].w};
#pragma unroll
            for (int q = 0; q < 4; ++q) {
                const float tk = tq[q];
                const float u  = oq[q] * LOG2E;
                const float e  = __builtin_amdgcn_exp2f(u);
                const bool pos = tk > 0.5f;
                const float tpk = pos ? tk : 0.0f;
                const float epk = pos ? e  : 0.0f;
                pcnt += __popcll(__ballot(pos));     // SALU-side positive count
                sneg += e - epk;                     // e on negatives (pads ~0)
                ta   += tk;
                tpos += tpk;
                aa    = fmaf(tk,  u, aa);            // sum t*u   (u-domain)
                ap    = fmaf(tpk, u, ap);            // sum tp*u  (u-domain)
                ep[4*it+q] = epk;
                tp[4*it+q] = tpk;
            }
        }
        const float S = wave_sum(sneg);              // only mid-row reduction

        // ---- Pass 2: no masks — sum over ALL slots, correct afterwards ----
        float lsum = 0.f, ltw = 0.f;
#pragma unroll
        for (int k = 0; k < 16; ++k) {
            const float l2 = __builtin_amdgcn_logf(S + ep[k]);   // log2
            lsum += l2;
            ltw   = fmaf(tp[k], l2, ltw);
        }

        // ---- One 5-chain reduction per row, scalar epilogue ----
        float red[5] = { ta - tpos, aa - ap, ap, lsum, ltw };
        wave_sum5(red);
        const float Tn = red[0], An = red[1], Apu = red[2], Ls = red[3], Lw = red[4];
        const float l2S = __builtin_amdgcn_logf(S);
        const float P   = (float)pcnt;

        float row_loss;
        if (pcnt > 0) {
            const float sum_lse2 = Ls - (1024.0f - P) * l2S;
            row_loss = LN2 * (fmaf(Tn, sum_lse2, Lw) - fmaf(P, An, Apu)) / P;
        } else {
            row_loss = LN2 * fmaf(Tn, l2S, -An);     // rare no-positive fallback
        }
        wacc += row_loss;
    }

    __shared__ float ls[WPB];
    if (lane == 0) ls[wave] = wacc;
    __syncthreads();
    if (threadIdx.x == 0)
        partial[blockIdx.x] = (ls[0] + ls[1]) + (ls[2] + ls[3]);
}

__global__ __launch_bounds__(256) void mvce_reduce(
    const float* __restrict__ partial, int n4, float inv_b, float* __restrict__ out)
{
    const float4* p4 = reinterpret_cast<const float4*>(partial);
    float s = 0.f;
#pragma unroll 2
    for (int i = threadIdx.x; i < n4; i += 256) {
        const float4 v = p4[i];
        s += (v.x + v.y) + (v.z + v.w);
    }
    s = wave_sum(s);
    __shared__ float ls[4];
    const int lane = threadIdx.x & 63;
    const int wave = threadIdx.x >> 6;
    if (lane == 0) ls[wave] = s;
    __syncthreads();
    if (threadIdx.x == 0) out[0] = ((ls[0] + ls[1]) + (ls[2] + ls[3])) * inv_b;
}

extern "C" void kernel_launch(void* const* d_in, const int* in_sizes, int n_in,
                              void* d_out, int out_size, void* d_ws, size_t ws_size,
                              hipStream_t stream) {
    const float* outp = (const float*)d_in[0];
    const float* tgtp = (const float*)d_in[1];
    const int Bn = in_sizes[0] / C_DIM;            // 65536
    const int nblocks = Bn / (WPB * RPW);          // 2048 partials -> 8 KB of d_ws
    float* partial = (float*)d_ws;

    mvce_rows<<<nblocks, 256, 0, stream>>>(outp, tgtp, partial);
    mvce_reduce<<<1, 256, 0, stream>>>(partial, nblocks / 4, 1.0f / (float)Bn,
                                       (float*)d_out);
}

// Round 3
// 505.387 us; speedup vs baseline: 1.0840x; 1.0840x over previous
//
#include <hip/hip_runtime.h>
#include <math.h>

// Problem shape (from reference setup_inputs): B=65536 rows, C=1000 cols, fp32.
#define C_DIM 1000
#define NV4   (C_DIM / 4)      // 250 float4 per row
#define WPB   4                // waves per block
#define RPW   8                // rows per wave, software-pipelined
#define PAD_O (-100.0f)        // exp2 flushes to 0; with t=0 contributes nothing
#define LOG2E 1.44269504088896340736f
#define LN2   0.69314718055994530942f

__device__ __forceinline__ float wave_sum(float v) {
#pragma unroll
    for (int off = 32; off > 0; off >>= 1)
        v += __shfl_xor(v, off, 64);
    return v;
}

// Five interleaved butterfly chains — DS latency overlapped 5-wide.
__device__ __forceinline__ void wave_sum5(float v[5]) {
#pragma unroll
    for (int off = 32; off > 0; off >>= 1) {
        float x[5];
#pragma unroll
        for (int i = 0; i < 5; ++i) x[i] = __shfl_xor(v[i], off, 64);
#pragma unroll
        for (int i = 0; i < 5; ++i) v[i] += x[i];
    }
}

// One wave = one row at a time, RPW rows sequentially. SINGLE raw buffer:
// pass 1 consumes ov/tv into ep/tp+stats, then row i+1's loads reuse the
// dead ov/tv registers, issued BEFORE the S-reduce + pass-2 + reduction
// block (~500 cycles of latency cover). Peak live ~80 VGPR — no spill
// (R2's double-buffer needed ~110 in a 96 budget -> 213 MB scratch traffic).
//
// Math (base-2 domain, u = o*log2e so exp->v_exp_f32, log->v_log_f32 raw):
//   S = sum_neg 2^u                    (only wave-reduced value needed mid-row)
//   pass2 over ALL 1024 slots: lsum = sum_k log2(S+ep_k), ltw = sum_k tp_k*log2(S+ep_k)
//   sum_p lse2_p = lsum - (1024-P)*log2(S)
//   sum_p loss_p = ln2*[ Tneg*sum_p lse2_p + ltw - P*aneg_u - apos_u ]
__global__ __launch_bounds__(256, 4) void mvce_rows(
    const float* __restrict__ outp, const float* __restrict__ tgtp,
    float* __restrict__ partial)
{
    const int lane = threadIdx.x & 63;
    const int wave = threadIdx.x >> 6;
    const size_t row0 = (size_t)(blockIdx.x * WPB + wave) * RPW;

    const float4* __restrict__ o4 = reinterpret_cast<const float4*>(outp) + row0 * NV4;
    const float4* __restrict__ t4 = reinterpret_cast<const float4*>(tgtp) + row0 * NV4;

    float4 ov[4], tv[4];

    // Prologue: load row 0.
#pragma unroll
    for (int it = 0; it < 4; ++it) {
        const int j = lane + 64 * it;
        if (j < NV4) { ov[it] = o4[j]; tv[it] = t4[j]; }
        else {
            ov[it] = make_float4(PAD_O, PAD_O, PAD_O, PAD_O);
            tv[it] = make_float4(0.f, 0.f, 0.f, 0.f);
        }
    }

    float wacc = 0.0f;

#pragma unroll
    for (int i = 0; i < RPW; ++i) {
        // ---- Pass 1 on row i: consume raw ov/tv -> ep/tp + stats ----
        float ep[16], tp[16];
        float sneg = 0.f, ta = 0.f, tpos = 0.f, aa = 0.f, ap = 0.f;
        int pcnt = 0;
#pragma unroll
        for (int it = 0; it < 4; ++it) {
            const float oq[4] = {ov[it].x, ov[it].y, ov[it].z, ov[it].w};
            const float tq[4] = {tv[it].x, tv[it].y, tv[it].z, tv[it].w};
#pragma unroll
            for (int q = 0; q < 4; ++q) {
                const float tk = tq[q];
                const float u  = oq[q] * LOG2E;
                const float e  = __builtin_amdgcn_exp2f(u);
                const bool pos = tk > 0.5f;
                const float tpk = pos ? tk : 0.0f;
                const float epk = pos ? e  : 0.0f;
                pcnt += __popcll(__ballot(pos));     // SALU-side positive count
                sneg += e - epk;                     // e on negatives (pads ~0)
                ta   += tk;
                tpos += tpk;
                aa    = fmaf(tk,  u, aa);            // sum t*u   (u-domain)
                ap    = fmaf(tpk, u, ap);            // sum tp*u  (u-domain)
                ep[4*it+q] = epk;
                tp[4*it+q] = tpk;
            }
        }

        // ---- Prefetch row i+1 into the now-dead raw registers ----
        if (i + 1 < RPW) {
            const float4* __restrict__ on = o4 + (size_t)(i + 1) * NV4;
            const float4* __restrict__ tn = t4 + (size_t)(i + 1) * NV4;
#pragma unroll
            for (int it = 0; it < 4; ++it) {
                const int j = lane + 64 * it;
                if (j < NV4) { ov[it] = on[j]; tv[it] = tn[j]; }
                else {
                    ov[it] = make_float4(PAD_O, PAD_O, PAD_O, PAD_O);
                    tv[it] = make_float4(0.f, 0.f, 0.f, 0.f);
                }
            }
        }
        __builtin_amdgcn_sched_barrier(0);   // loads stay above the compute tail

        // ---- S-reduce + Pass 2 + final reduction (covers prefetch latency) ----
        const float S = wave_sum(sneg);

        float lsum = 0.f, ltw = 0.f;
#pragma unroll
        for (int k = 0; k < 16; ++k) {
            const float l2 = __builtin_amdgcn_logf(S + ep[k]);   // log2
            lsum += l2;
            ltw   = fmaf(tp[k], l2, ltw);
        }

        float red[5] = { ta - tpos, aa - ap, ap, lsum, ltw };
        wave_sum5(red);
        const float Tn = red[0], An = red[1], Apu = red[2], Ls = red[3], Lw = red[4];
        const float l2S = __builtin_amdgcn_logf(S);
        const float P   = (float)pcnt;

        float row_loss;
        if (pcnt > 0) {
            const float sum_lse2 = Ls - (1024.0f - P) * l2S;
            row_loss = LN2 * (fmaf(Tn, sum_lse2, Lw) - fmaf(P, An, Apu)) / P;
        } else {
            row_loss = LN2 * fmaf(Tn, l2S, -An);     // rare no-positive fallback
        }
        wacc += row_loss;
    }

    __shared__ float ls[WPB];
    if (lane == 0) ls[wave] = wacc;
    __syncthreads();
    if (threadIdx.x == 0)
        partial[blockIdx.x] = (ls[0] + ls[1]) + (ls[2] + ls[3]);
}

__global__ __launch_bounds__(256) void mvce_reduce(
    const float* __restrict__ partial, int n4, float inv_b, float* __restrict__ out)
{
    const float4* p4 = reinterpret_cast<const float4*>(partial);
    float s = 0.f;
#pragma unroll 2
    for (int i = threadIdx.x; i < n4; i += 256) {
        const float4 v = p4[i];
        s += (v.x + v.y) + (v.z + v.w);
    }
    s = wave_sum(s);
    __shared__ float ls[4];
    const int lane = threadIdx.x & 63;
    const int wave = threadIdx.x >> 6;
    if (lane == 0) ls[wave] = s;
    __syncthreads();
    if (threadIdx.x == 0) out[0] = ((ls[0] + ls[1]) + (ls[2] + ls[3])) * inv_b;
}

extern "C" void kernel_launch(void* const* d_in, const int* in_sizes, int n_in,
                              void* d_out, int out_size, void* d_ws, size_t ws_size,
                              hipStream_t stream) {
    const float* outp = (const float*)d_in[0];
    const float* tgtp = (const float*)d_in[1];
    const int Bn = in_sizes[0] / C_DIM;            // 65536
    const int nblocks = Bn / (WPB * RPW);          // 2048 partials -> 8 KB of d_ws
    float* partial = (float*)d_ws;

    mvce_rows<<<nblocks, 256, 0, stream>>>(outp, tgtp, partial);
    mvce_reduce<<<1, 256, 0, stream>>>(partial, nblocks / 4, 1.0f / (float)Bn,
                                       (float*)d_out);
}